// Round 1
// baseline (5781.190 us; speedup 1.0000x reference)
//
#include <hip/hip_runtime.h>

#define B_ 64
#define T_ 4096
#define D_ 128
#define H_ 256

// ---------------------------------------------------------------------------
// Kernel A: xp = x @ Wx + bx, written into `out` (later overwritten by h).
// grid = (B*T)/64 blocks, 256 threads. Each block: 64 rows x 256 cols.
// x tile (64x128 fp32 = 32 KB) staged in LDS; Wx (128 KB) streamed from L2.
// ---------------------------------------------------------------------------
__global__ __launch_bounds__(256) void xp_kernel(const float* __restrict__ x,
                                                 const float* __restrict__ Wx,
                                                 const float* __restrict__ bx,
                                                 float* __restrict__ out) {
    __shared__ float xs[64 * D_];
    const int j = threadIdx.x;                 // output column 0..255
    const long row0 = (long)blockIdx.x * 64;

    // contiguous 8192-float tile load, float4-vectorized
    const float4* xg = (const float4*)(x + row0 * D_);
    float4* xs4 = (float4*)xs;
    for (int i = j; i < (64 * D_) / 4; i += 256) xs4[i] = xg[i];
    __syncthreads();

    float acc[64];
#pragma unroll
    for (int r = 0; r < 64; ++r) acc[r] = 0.f;

    for (int k0 = 0; k0 < D_; k0 += 4) {
        const float w0 = Wx[(k0 + 0) * H_ + j];
        const float w1 = Wx[(k0 + 1) * H_ + j];
        const float w2 = Wx[(k0 + 2) * H_ + j];
        const float w3 = Wx[(k0 + 3) * H_ + j];
#pragma unroll
        for (int r = 0; r < 64; ++r) {
            const float4 xv = *(const float4*)(&xs[r * D_ + k0]);  // LDS broadcast
            acc[r] += xv.x * w0 + xv.y * w1 + xv.z * w2 + xv.w * w3;
        }
    }

    const float bj = bx[j];
    for (int r = 0; r < 64; ++r) {
        out[(row0 + r) * H_ + j] = acc[r] + bj;   // coalesced across j
    }
}

// ---------------------------------------------------------------------------
// Kernel B: per-batch recurrence h_t = tanh(xp_t + h_{t-1} @ Wh + bh).
// grid = 64 blocks (one per batch element), 1024 threads (16 waves).
// Thread (j = tid&255, q = tid>>8) holds Wh[64q .. 64q+63][j] in registers.
// h lives in LDS (broadcast b128 reads); 4 partials reduced via LDS.
// xp for step t+1 is prefetched while computing step t's dot products.
// ---------------------------------------------------------------------------
__global__ __launch_bounds__(1024) void rnn_kernel(const float* __restrict__ Wh,
                                                   const float* __restrict__ bh,
                                                   float* __restrict__ out) {
    const int b = blockIdx.x;
    const int tid = threadIdx.x;
    const int j = tid & 255;
    const int q = tid >> 8;                    // 0..3

    __shared__ float hs[H_];
    __shared__ float partial[4 * H_];

    // Wh column j, rows [64q, 64q+64) -> registers (coalesced across j)
    float wreg[64];
#pragma unroll
    for (int ii = 0; ii < 64; ++ii) wreg[ii] = Wh[(q * 64 + ii) * H_ + j];
    const float bhj = bh[j];

    if (tid < H_) hs[tid] = 0.f;
    __syncthreads();

    float* obase = out + (long)b * T_ * H_;
    float xp_cur = 0.f, xp_next = 0.f;
    if (q == 0) xp_cur = obase[j];             // xp[b][0][j]

    for (int t = 0; t < T_; ++t) {
        // prefetch next step's xp while we do this step's dot product
        if (q == 0 && t + 1 < T_) xp_next = obase[(long)(t + 1) * H_ + j];

        float a0 = 0.f, a1 = 0.f, a2 = 0.f, a3 = 0.f;
#pragma unroll
        for (int ii = 0; ii < 64; ii += 4) {
            const float4 hv = *(const float4*)(&hs[q * 64 + ii]);  // broadcast
            a0 += hv.x * wreg[ii + 0];
            a1 += hv.y * wreg[ii + 1];
            a2 += hv.z * wreg[ii + 2];
            a3 += hv.w * wreg[ii + 3];
        }
        partial[q * H_ + j] = (a0 + a1) + (a2 + a3);
        __syncthreads();

        if (q == 0) {
            float s = partial[j] + partial[H_ + j] + partial[2 * H_ + j] +
                      partial[3 * H_ + j] + xp_cur + bhj;
            const float hnew = tanhf(s);
            obase[(long)t * H_ + j] = hnew;    // coalesced store
            hs[j] = hnew;
            xp_cur = xp_next;
        }
        __syncthreads();
    }
}

extern "C" void kernel_launch(void* const* d_in, const int* in_sizes, int n_in,
                              void* d_out, int out_size, void* d_ws, size_t ws_size,
                              hipStream_t stream) {
    const float* x  = (const float*)d_in[0];
    const float* Wx = (const float*)d_in[1];
    const float* bx = (const float*)d_in[2];
    const float* Wh = (const float*)d_in[3];
    const float* bh = (const float*)d_in[4];
    float* out = (float*)d_out;

    xp_kernel<<<(B_ * T_) / 64, 256, 0, stream>>>(x, Wx, bx, out);
    rnn_kernel<<<B_, 1024, 0, stream>>>(Wh, bh, out);
}

// Round 2
// 3731.801 us; speedup vs baseline: 1.5492x; 1.5492x over previous
//
#include <hip/hip_runtime.h>

#define B_ 64
#define T_ 4096
#define D_ 128
#define H_ 256

// Barrier that waits only on LDS ops (lgkmcnt), NOT on in-flight global
// loads/stores (vmcnt). __syncthreads() would drain vmcnt(0) every step,
// serializing the xp prefetch (HBM ~900 cyc) and h store retire into the
// critical path. Our per-step cross-thread hazards are LDS-only.
__device__ __forceinline__ void barrier_lgkm() {
    asm volatile("s_waitcnt lgkmcnt(0)\n\ts_barrier" ::: "memory");
}

// ---------------------------------------------------------------------------
// Kernel A: xp = x @ Wx + bx, written into `out`.
// grid = (B*T)/64 blocks, 1024 threads (16 waves -> 4/SIMD latency hiding).
// Thread (j = tid&255, q = tid>>8) computes rows [16q,16q+16) x column j.
// x tile (64x128 fp32 = 32 KB) in LDS; Wx (131 KB) stays L2-hot.
// ---------------------------------------------------------------------------
__global__ __launch_bounds__(1024) void xp_kernel(const float* __restrict__ x,
                                                  const float* __restrict__ Wx,
                                                  const float* __restrict__ bx,
                                                  float* __restrict__ out) {
    __shared__ float xs[64 * D_];
    const int tid = threadIdx.x;
    const int j = tid & 255;
    const int q = tid >> 8;                    // 0..3 -> rows 16q..16q+15
    const long row0 = (long)blockIdx.x * 64;

    // contiguous 8192-float tile load, float4-vectorized (2 per thread)
    const float4* xg = (const float4*)(x + row0 * D_);
    float4* xs4 = (float4*)xs;
    for (int i = tid; i < (64 * D_) / 4; i += 1024) xs4[i] = xg[i];
    __syncthreads();

    float acc[16];
#pragma unroll
    for (int r = 0; r < 16; ++r) acc[r] = 0.f;

    for (int k0 = 0; k0 < D_; k0 += 4) {
        const float w0 = Wx[(k0 + 0) * H_ + j];
        const float w1 = Wx[(k0 + 1) * H_ + j];
        const float w2 = Wx[(k0 + 2) * H_ + j];
        const float w3 = Wx[(k0 + 3) * H_ + j];
#pragma unroll
        for (int r = 0; r < 16; ++r) {
            const float4 xv = *(const float4*)(&xs[(q * 16 + r) * D_ + k0]);  // broadcast
            acc[r] += xv.x * w0 + xv.y * w1 + xv.z * w2 + xv.w * w3;
        }
    }

    const float bj = bx[j];
#pragma unroll
    for (int r = 0; r < 16; ++r) {
        out[(row0 + q * 16 + r) * H_ + j] = acc[r] + bj;   // coalesced across j
    }
}

// ---------------------------------------------------------------------------
// Kernel B: per-batch recurrence h_t = tanh(xp_t + h_{t-1} @ Wh + bh).
// grid = 64 blocks, 1024 threads. Thread (j, q) holds Wh[64q..64q+63][j]
// in registers. Per step: broadcast ds_read of h slice -> 64 FMAs ->
// partial via LDS (q!=0 only; q==0 keeps its own in reg) -> lgkm barrier ->
// q==0 reduces + fast tanh + store -> lgkm barrier. Global xp prefetch and
// h stores stay in flight across barriers (no vmcnt drain).
// ---------------------------------------------------------------------------
__global__ __launch_bounds__(1024) void rnn_kernel(const float* __restrict__ Wh,
                                                   const float* __restrict__ bh,
                                                   float* __restrict__ out) {
    const int b = blockIdx.x;
    const int tid = threadIdx.x;
    const int j = tid & 255;
    const int q = tid >> 8;                    // 0..3

    __shared__ float hs[H_];
    __shared__ float partial[3 * H_];          // written by q=1..3

    float wreg[64];
#pragma unroll
    for (int ii = 0; ii < 64; ++ii) wreg[ii] = Wh[(q * 64 + ii) * H_ + j];
    const float bhj = bh[j];

    if (tid < H_) hs[tid] = 0.f;
    __syncthreads();                           // once; vmcnt drain here is fine

    float* obase = out + (long)b * T_ * H_;
    float xp0 = 0.f, xp1 = 0.f;
    if (q == 0) {
        xp0 = obase[j];                        // xp[b][0][j]
        xp1 = obase[H_ + j];                   // xp[b][1][j]
    }

#pragma unroll 2
    for (int t = 0; t < T_; ++t) {
        // prefetch xp for t+2; vmcnt wait lands ~1 full step later
        float xp2 = 0.f;
        if (q == 0 && t + 2 < T_) xp2 = obase[(long)(t + 2) * H_ + j];

        float a0 = 0.f, a1 = 0.f, a2 = 0.f, a3 = 0.f;
#pragma unroll
        for (int ii = 0; ii < 64; ii += 4) {
            const float4 hv = *(const float4*)(&hs[q * 64 + ii]);  // broadcast
            a0 += hv.x * wreg[ii + 0];
            a1 += hv.y * wreg[ii + 1];
            a2 += hv.z * wreg[ii + 2];
            a3 += hv.w * wreg[ii + 3];
        }
        const float p = (a0 + a1) + (a2 + a3);
        if (q != 0) partial[(q - 1) * H_ + j] = p;
        barrier_lgkm();

        if (q == 0) {
            float s = p + partial[j] + partial[H_ + j] + partial[2 * H_ + j]
                      + xp0 + bhj;
            // branchless tanh: clamp, e = exp(2s), (e-1)/(e+1)
            s = fminf(15.f, fmaxf(-15.f, s));
            const float e = __expf(2.f * s);
            const float hn = __fdividef(e - 1.f, e + 1.f);
            hs[j] = hn;
            obase[(long)t * H_ + j] = hn;      // fire-and-forget store
            xp0 = xp1;
            xp1 = xp2;
        }
        barrier_lgkm();
    }
}

extern "C" void kernel_launch(void* const* d_in, const int* in_sizes, int n_in,
                              void* d_out, int out_size, void* d_ws, size_t ws_size,
                              hipStream_t stream) {
    const float* x  = (const float*)d_in[0];
    const float* Wx = (const float*)d_in[1];
    const float* bx = (const float*)d_in[2];
    const float* Wh = (const float*)d_in[3];
    const float* bh = (const float*)d_in[4];
    float* out = (float*)d_out;

    xp_kernel<<<(B_ * T_) / 64, 1024, 0, stream>>>(x, Wx, bx, out);
    rnn_kernel<<<B_, 1024, 0, stream>>>(Wh, bh, out);
}